// Round 10
// baseline (115.584 us; speedup 1.0000x reference)
//
#include <hip/hip_runtime.h>
#include <hip/hip_bf16.h>
#include <math.h>

constexpr int D      = 2048;
constexpr int NE     = 64;
constexpr int TOKENS = 16384;   // 4*4096
constexpr int TPB    = 64;      // tokens per block -> 256 blocks, 1/CU
constexpr int NBLK   = TOKENS / TPB;
constexpr int NSL    = 8;       // k-slices (frozen split)
constexpr int KSLICE = D / NSL; // 256 floats = 1 KB per row
constexpr int KC     = 32;      // k per MFMA step
constexpr int NKC    = KSLICE / KC; // 8
constexpr int PAD    = 66;

typedef __attribute__((ext_vector_type(8))) short bf16x8;
typedef __attribute__((ext_vector_type(4))) float f32x4;

static __device__ inline unsigned short f2bf_u(float x) {
  __hip_bfloat16 h = __float2bfloat16(x);   // RNE
  unsigned short u; __builtin_memcpy(&u, &h, 2); return u;
}
static __device__ inline float bfu2f(unsigned short u) {
  __hip_bfloat16 h; __builtin_memcpy(&h, &u, 2);
  return __bfloat162float(h);
}

// split 8 f32 into hi/lo bf16 — bit-identical to rounds 2-9
static __device__ inline void cvt_hilo(const float* f, bf16x8& hi, bf16x8& lo) {
#pragma unroll
  for (int j = 0; j < 8; ++j) {
    unsigned short h = f2bf_u(f[j]);
    float hf = bfu2f(h);
    unsigned short lw = f2bf_u(f[j] - hf);
    hi[j] = (short)h;
    lo[j] = (short)lw;
  }
}

// pre-kernel: W (64x2048 f32) -> Whi/Wlo bf16 (bit-identical split)
__global__ __launch_bounds__(256)
void prep_w(const float* __restrict__ W, unsigned short* __restrict__ Whi,
            unsigned short* __restrict__ Wlo) {
  const int i = (blockIdx.x * 256 + threadIdx.x) * 4;
  float4 v = *reinterpret_cast<const float4*>(W + i);
  float f[4] = {v.x, v.y, v.z, v.w};
#pragma unroll
  for (int j = 0; j < 4; ++j) {
    unsigned short h = f2bf_u(f[j]);
    float hf = bfu2f(h);
    Whi[i + j] = h;
    Wlo[i + j] = f2bf_u(f[j] - hf);
  }
}

__global__ __launch_bounds__(512, 2)
void router_main(const float* __restrict__ X,
                 const unsigned short* __restrict__ Whi,
                 const unsigned short* __restrict__ Wlo,
                 const float* __restrict__ bias,
                 float* __restrict__ out) {
  // X slice double-buffer: [2][64 rows][1 KB], source-swizzled (logical byte b of
  // row r lives at LDS byte b ^ ((r&7)<<4)) -> conflict-free b128 frag reads.
  __shared__ __align__(16) float xbuf[2][TPB * KSLICE / 1];  // 2 * 64 KB  (indexed manually)
  __shared__ float red[TPB][PAD];                            // 16.9 KB per-slice partials
  __shared__ int   i1s[TPB], i2s[TPB];
  __shared__ float p1s[TPB], p2s[TPB];

  const int t  = threadIdx.x;
  const int wv = t >> 6;        // wave 0..7
  const int mh = wv >> 1;       // m-tile 0..3 (tokens mh*16..+16)
  const int nh = wv & 1;        // n-half: n-tiles {2nh, 2nh+1}
  const int l  = t & 63;
  const int lm = l & 15;        // M-row / N-col in 16x16 tile
  const int lk = l >> 4;        // k-group -> k offset lk*8
  // XCD swizzle (round 8): xcd = bid%8 gets contiguous token range
  const int tile = (blockIdx.x & 7) * (NBLK / 8) + (blockIdx.x >> 3);
  const int tok0 = tile * TPB;

  // W fragment pointers: expert rows (2nh+n)*16+lm — shared by the 4 mh-waves (L1 reuse)
  const unsigned short* whp[2];
#pragma unroll
  for (int n = 0; n < 2; ++n)
    whp[n] = Whi + (size_t)((nh * 2 + n) * 16 + lm) * D + lk * 8;

  // staging: wave stages rows wv*8..wv*8+7; lane reads 16B at swizzled col offset
  // -> each wave-instruction covers one CONTIGUOUS 1 KB global chunk.
  float4 g[8];
  auto issue_loads = [&](int ss) {
#pragma unroll
    for (int j = 0; j < 8; ++j) {
      const int r = wv * 8 + j;
      const char* rowsrc = reinterpret_cast<const char*>(
          X + (size_t)(tok0 + r) * D + ss * KSLICE);
      g[j] = *reinterpret_cast<const float4*>(rowsrc + ((l * 16) ^ ((r & 7) << 4)));
    }
  };
  auto write_lds = [&](int nb) {
#pragma unroll
    for (int j = 0; j < 8; ++j) {
      const int r = wv * 8 + j;
      char* rowdst = reinterpret_cast<char*>(&xbuf[nb][r * KSLICE]);
      *reinterpret_cast<float4*>(rowdst + l * 16) = g[j];   // linear write (swz in src)
    }
  };

  issue_loads(0);
  write_lds(0);
  __syncthreads();

  const int rtok = t >> 3;          // 0..63
  const int re0  = (t & 7) * 8;     // 0..56
  float sreg[8];
#pragma unroll
  for (int q = 0; q < 8; ++q) sreg[q] = bias[re0 + q];   // bias first (frozen order)

  int cb = 0;
#pragma unroll 1
  for (int s = 0; s < NSL; ++s) {
    if (s < NSL - 1) issue_loads(s + 1);     // async: in flight across compute (T14)

    // ---- compute slice s: frozen per-(tok,e,slice) chain: kc 0..7, hh/hl/lh/ll ----
    f32x4 acc[2];
#pragma unroll
    for (int n = 0; n < 2; ++n) acc[n] = (f32x4){0.f, 0.f, 0.f, 0.f};

    const int row = mh * 16 + lm;
    const int sw  = (row & 7) << 4;
    const char* rb = reinterpret_cast<const char*>(&xbuf[cb][row * KSLICE]);

#pragma unroll
    for (int kc = 0; kc < NKC; ++kc) {
      bf16x8 bh[2], bl[2];
#pragma unroll
      for (int n = 0; n < 2; ++n) {
        const unsigned short* wp = whp[n] + (size_t)s * KSLICE + kc * KC;
        bh[n] = *reinterpret_cast<const bf16x8*>(wp);
        bl[n] = *reinterpret_cast<const bf16x8*>(wp + (size_t)NE * D);
      }
      const int b = kc * 128 + lk * 32;
      float f[8];
      *reinterpret_cast<float4*>(&f[0]) =
          *reinterpret_cast<const float4*>(rb + (b ^ sw));
      *reinterpret_cast<float4*>(&f[4]) =
          *reinterpret_cast<const float4*>(rb + ((b + 16) ^ sw));
      bf16x8 ah, al;
      cvt_hilo(f, ah, al);
#pragma unroll
      for (int n = 0; n < 2; ++n) {          // same hh,hl,lh,ll order as rounds 2-9
        acc[n] = __builtin_amdgcn_mfma_f32_16x16x32_bf16(ah, bh[n], acc[n], 0, 0, 0);
        acc[n] = __builtin_amdgcn_mfma_f32_16x16x32_bf16(ah, bl[n], acc[n], 0, 0, 0);
        acc[n] = __builtin_amdgcn_mfma_f32_16x16x32_bf16(al, bh[n], acc[n], 0, 0, 0);
        acc[n] = __builtin_amdgcn_mfma_f32_16x16x32_bf16(al, bl[n], acc[n], 0, 0, 0);
      }
    }

    if (s < NSL - 1) write_lds(cb ^ 1);      // loads have had the whole slice to land

    // ---- stash slice-s partials (same C->slot mapping as rounds 2-9) ----
#pragma unroll
    for (int n = 0; n < 2; ++n)
#pragma unroll
      for (int j = 0; j < 4; ++j)
        red[mh * 16 + lk * 4 + j][(nh * 2 + n) * 16 + lm] = acc[n][j];
    __syncthreads();                          // red + xbuf[cb^1] published

    // ---- mini-reduce, slice order: sreg = bias + p0 + p1 + ... (frozen order) ----
#pragma unroll
    for (int q = 0; q < 8; ++q) sreg[q] += red[rtok][re0 + q];
    __syncthreads();                          // red free for next slice
    cb ^= 1;
  }

  // ---- final logits back to LDS (own slots), then frozen epilogue ----
#pragma unroll
  for (int q = 0; q < 8; ++q) red[rtok][re0 + q] = sreg[q];
  __syncthreads();

  if (t < TPB) {
    float m1 = -INFINITY, m2 = -INFINITY;
    int j1 = 0, j2 = 0;
    for (int e = 0; e < NE; ++e) {
      const float v = red[t][e];
      if (v > m1) { m2 = m1; j2 = j1; m1 = v; j1 = e; }     // strict >: lax.top_k tie-break
      else if (v > m2) { m2 = v; j2 = e; }
    }
    const float e2  = expf(m2 - m1);
    const float inv = 1.0f / (1.0f + e2);
    i1s[t] = j1; i2s[t] = j2;
    p1s[t] = inv; p2s[t] = e2 * inv;
    float* oidx = out + (size_t)TOKENS * NE + (size_t)(tok0 + t) * 2;
    oidx[0] = (float)j1;
    oidx[1] = (float)j2;
  }
  __syncthreads();

  // coalesced sf write: 512 thr -> (token = t>>3, experts 8*(t&7)..+7)
  {
    const int tok = t >> 3;
    const int e0  = (t & 7) * 8;
    const int j1 = i1s[tok], j2 = i2s[tok];
    const float pa = p1s[tok], pb2 = p2s[tok];
    float vv[8];
#pragma unroll
    for (int q = 0; q < 8; ++q) {
      const int e = e0 + q;
      vv[q] = (e == j1) ? pa : ((e == j2) ? pb2 : 0.f);
    }
    float* obase = out + (size_t)(tok0 + tok) * NE + e0;
    *reinterpret_cast<float4*>(obase)     = make_float4(vv[0], vv[1], vv[2], vv[3]);
    *reinterpret_cast<float4*>(obase + 4) = make_float4(vv[4], vv[5], vv[6], vv[7]);
  }
}

extern "C" void kernel_launch(void* const* d_in, const int* in_sizes, int n_in,
                              void* d_out, int out_size, void* d_ws, size_t ws_size,
                              hipStream_t stream) {
  const float* X = (const float*)d_in[0];
  const float* W = (const float*)d_in[1];
  const float* B = (const float*)d_in[2];
  float* out = (float*)d_out;

  unsigned short* Whi = (unsigned short*)d_ws;     // 256 KB
  unsigned short* Wlo = Whi + (size_t)NE * D;      // 256 KB

  prep_w<<<dim3(NE * D / (256 * 4)), dim3(256), 0, stream>>>(W, Whi, Wlo);
  router_main<<<dim3(NBLK), dim3(512), 0, stream>>>(X, Whi, Wlo, B, out);
}

// Round 11
// 60.568 us; speedup vs baseline: 1.9083x; 1.9083x over previous
//
#include <hip/hip_runtime.h>
#include <hip/hip_bf16.h>
#include <math.h>

constexpr int D      = 2048;
constexpr int NE     = 64;
constexpr int TOKENS = 16384;   // 4*4096
constexpr int TPB    = 64;      // tokens per block -> 256 blocks, 1/CU
constexpr int NBLK   = TOKENS / TPB;
constexpr int NSL    = 8;       // k-slices (frozen split)
constexpr int KSLICE = D / NSL; // 256 floats = 1 KB per row
constexpr int KC     = 32;      // k per MFMA step
constexpr int NKC    = KSLICE / KC; // 8
constexpr int PAD    = 66;

typedef __attribute__((ext_vector_type(8))) short bf16x8;
typedef __attribute__((ext_vector_type(4))) float f32x4;

static __device__ inline unsigned short f2bf_u(float x) {
  __hip_bfloat16 h = __float2bfloat16(x);   // RNE
  unsigned short u; __builtin_memcpy(&u, &h, 2); return u;
}
static __device__ inline float bfu2f(unsigned short u) {
  __hip_bfloat16 h; __builtin_memcpy(&h, &u, 2);
  return __bfloat162float(h);
}

// split into hi/lo bf16 — bit-identical values to rounds 2-10
static __device__ inline void cvt_hilo(const float* f, bf16x8& hi, bf16x8& lo) {
#pragma unroll
  for (int j = 0; j < 8; ++j) {
    unsigned short h = f2bf_u(f[j]);
    float hf = bfu2f(h);
    unsigned short lw = f2bf_u(f[j] - hf);
    hi[j] = (short)h;
    lo[j] = (short)lw;
  }
}

// pre-kernel: W -> FRAGMENT-MAJOR Whi/Wlo store: fragment (s,kc,ntile,hl) is 1 KB
// contiguous (64 lanes x 16B) in the exact order the main loop consumes it.
// Values bit-identical to rounds 2-10; only the storage location changes.
__global__ __launch_bounds__(256)
void prep_w(const float* __restrict__ W, unsigned short* __restrict__ WF) {
  const int i = (blockIdx.x * 256 + threadIdx.x) * 4;
  float4 v = *reinterpret_cast<const float4*>(W + i);
  float f[4] = {v.x, v.y, v.z, v.w};
  const int e  = i / D;            // constant across the 4 elems (D % 4 == 0)
  const int lm = e & 15, nt = e >> 4;
#pragma unroll
  for (int j = 0; j < 4; ++j) {
    const int k  = (i + j) % D;
    const int s  = k >> 8;           // k-slice
    const int kc = (k >> 5) & 7;     // 32-k step
    const int lk = (k >> 3) & 3;     // k-group
    const int jj = k & 7;
    const int lane = lk * 16 + lm;
    const size_t base = ((size_t)((s * 8 + kc) * 4 + nt) * 2) * 512 + (size_t)lane * 8 + jj;
    unsigned short h = f2bf_u(f[j]);
    float hf = bfu2f(h);
    WF[base]       = h;                    // hi  (hl=0)
    WF[base + 512] = f2bf_u(f[j] - hf);    // lo  (hl=1, next 1 KB fragment)
  }
}

__global__ __launch_bounds__(512, 2)
void router_main(const float* __restrict__ X,
                 const unsigned short* __restrict__ WF,
                 const float* __restrict__ bias,
                 float* __restrict__ out) {
  // X slice double-buffer (128 KB): LDS[row][b] = G[row][b ^ ((row&7)<<4)]
  // (linear gload_lds dest + inverse-swizzled global source; read applies ^sw)
  __shared__ __align__(16) float xbuf[2][TPB * KSLICE];
  __shared__ float red[TPB][PAD];          // per-slice partials (16.9 KB)
  __shared__ int   i1s[TPB], i2s[TPB];
  __shared__ float p1s[TPB], p2s[TPB];

  const int t  = threadIdx.x;
  const int wv = t >> 6;        // wave 0..7
  const int mh = wv >> 1;       // m-tile (tokens mh*16..+15)
  const int nh = wv & 1;        // n-half: n-tiles {2nh, 2nh+1}
  const int l  = t & 63;
  const int lm = l & 15;
  const int lk = l >> 4;
  const int tile = (blockIdx.x & 7) * (NBLK / 8) + (blockIdx.x >> 3);  // XCD swizzle
  const int tok0 = tile * TPB;

  // stage slice ss into xbuf[nb]: wave wv stages rows wv*8..+7; one gload_lds =
  // one contiguous 1 KB global chunk -> LDS base + lane*16 (linear).
  auto stage = [&](int nb, int ss) {
#pragma unroll
    for (int j = 0; j < 8; ++j) {
      const int r = wv * 8 + j;
      const char* src = reinterpret_cast<const char*>(
          X + (size_t)(tok0 + r) * D + ss * KSLICE) + ((l * 16) ^ ((r & 7) << 4));
      __builtin_amdgcn_global_load_lds(
          (const __attribute__((address_space(1))) unsigned int*)src,
          (__attribute__((address_space(3))) unsigned int*)&xbuf[nb][r * KSLICE],
          16, 0, 0);
    }
  };

  stage(0, 0);
  __syncthreads();                 // barrier drains vmcnt(0): slice 0 resident

  const int rtok = t >> 3;         // 0..63
  const int re0  = (t & 7) * 8;    // 0..56
  float sreg[8];
#pragma unroll
  for (int q = 0; q < 8; ++q) sreg[q] = bias[re0 + q];   // bias first (frozen order)

  const int row = mh * 16 + lm;
  const int sw  = (row & 7) << 4;

  int cb = 0;
#pragma unroll 1
  for (int s = 0; s < NSL; ++s) {
    f32x4 acc[2];
#pragma unroll
    for (int n = 0; n < 2; ++n) acc[n] = (f32x4){0.f, 0.f, 0.f, 0.f};

    const char* rb = reinterpret_cast<const char*>(&xbuf[cb][row * KSLICE]);

#pragma unroll
    for (int kc = 0; kc < NKC; ++kc) {
      // W fragments: 4 KB contiguous (fragment-major layout) — no L1 set aliasing
      const unsigned short* gb = WF + ((size_t)((s * 8 + kc) * 8 + nh * 4)) * 512
                                    + (size_t)l * 8;
      bf16x8 bh[2], bl[2];
      bh[0] = *reinterpret_cast<const bf16x8*>(gb);
      bl[0] = *reinterpret_cast<const bf16x8*>(gb + 512);
      bh[1] = *reinterpret_cast<const bf16x8*>(gb + 1024);
      bl[1] = *reinterpret_cast<const bf16x8*>(gb + 1536);

      const int b = kc * 128 + lk * 32;
      float f[8];
      *reinterpret_cast<float4*>(&f[0]) =
          *reinterpret_cast<const float4*>(rb + (b ^ sw));
      *reinterpret_cast<float4*>(&f[4]) =
          *reinterpret_cast<const float4*>(rb + ((b + 16) ^ sw));
      bf16x8 ah, al;
      cvt_hilo(f, ah, al);
#pragma unroll
      for (int n = 0; n < 2; ++n) {          // frozen hh,hl,lh,ll order
        acc[n] = __builtin_amdgcn_mfma_f32_16x16x32_bf16(ah, bh[n], acc[n], 0, 0, 0);
        acc[n] = __builtin_amdgcn_mfma_f32_16x16x32_bf16(ah, bl[n], acc[n], 0, 0, 0);
        acc[n] = __builtin_amdgcn_mfma_f32_16x16x32_bf16(al, bh[n], acc[n], 0, 0, 0);
        acc[n] = __builtin_amdgcn_mfma_f32_16x16x32_bf16(al, bl[n], acc[n], 0, 0, 0);
      }
    }

    // prefetch next slice AFTER all W consumption (in-order vmcnt: stagers must
    // not precede W loads); lands during stash, drained at the barrier.
    if (s < NSL - 1) stage(cb ^ 1, s + 1);

    // stash slice-s partials (same C->slot mapping as rounds 2-10)
#pragma unroll
    for (int n = 0; n < 2; ++n)
#pragma unroll
      for (int j = 0; j < 4; ++j)
        red[mh * 16 + lk * 4 + j][(nh * 2 + n) * 16 + lm] = acc[n][j];
    __syncthreads();                          // red visible + staged slice resident

    // sreg = bias + p0 + p1 + ... (frozen left-to-right slice order)
#pragma unroll
    for (int q = 0; q < 8; ++q) sreg[q] += red[rtok][re0 + q];
    __syncthreads();                          // red free for next slice
    cb ^= 1;
  }

  // final logits to LDS (own slots), then frozen epilogue
#pragma unroll
  for (int q = 0; q < 8; ++q) red[rtok][re0 + q] = sreg[q];
  __syncthreads();

  if (t < TPB) {
    float m1 = -INFINITY, m2 = -INFINITY;
    int j1 = 0, j2 = 0;
    for (int e = 0; e < NE; ++e) {
      const float v = red[t][e];
      if (v > m1) { m2 = m1; j2 = j1; m1 = v; j1 = e; }     // strict >: lax.top_k tie-break
      else if (v > m2) { m2 = v; j2 = e; }
    }
    const float e2  = expf(m2 - m1);
    const float inv = 1.0f / (1.0f + e2);
    i1s[t] = j1; i2s[t] = j2;
    p1s[t] = inv; p2s[t] = e2 * inv;
    float* oidx = out + (size_t)TOKENS * NE + (size_t)(tok0 + t) * 2;
    oidx[0] = (float)j1;
    oidx[1] = (float)j2;
  }
  __syncthreads();

  // coalesced sf write: 512 thr -> (token = t>>3, experts 8*(t&7)..+7)
  {
    const int tok = t >> 3;
    const int e0  = (t & 7) * 8;
    const int j1 = i1s[tok], j2 = i2s[tok];
    const float pa = p1s[tok], pb2 = p2s[tok];
    float vv[8];
#pragma unroll
    for (int q = 0; q < 8; ++q) {
      const int e = e0 + q;
      vv[q] = (e == j1) ? pa : ((e == j2) ? pb2 : 0.f);
    }
    float* obase = out + (size_t)(tok0 + tok) * NE + e0;
    *reinterpret_cast<float4*>(obase)     = make_float4(vv[0], vv[1], vv[2], vv[3]);
    *reinterpret_cast<float4*>(obase + 4) = make_float4(vv[4], vv[5], vv[6], vv[7]);
  }
}

extern "C" void kernel_launch(void* const* d_in, const int* in_sizes, int n_in,
                              void* d_out, int out_size, void* d_ws, size_t ws_size,
                              hipStream_t stream) {
  const float* X = (const float*)d_in[0];
  const float* W = (const float*)d_in[1];
  const float* B = (const float*)d_in[2];
  float* out = (float*)d_out;

  unsigned short* WF = (unsigned short*)d_ws;   // 512 KB fragment-major Whi/Wlo

  prep_w<<<dim3(NE * D / (256 * 4)), dim3(256), 0, stream>>>(W, WF);
  router_main<<<dim3(NBLK), dim3(512), 0, stream>>>(X, WF, B, out);
}

// Round 12
// 43.876 us; speedup vs baseline: 2.6343x; 1.3804x over previous
//
#include <hip/hip_runtime.h>
#include <hip/hip_bf16.h>
#include <math.h>

constexpr int D      = 2048;
constexpr int NE     = 64;
constexpr int TOKENS = 16384;   // 4*4096
constexpr int TPB    = 64;      // tokens per block -> 256 blocks, 1/CU, no tail
constexpr int NBLK   = TOKENS / TPB;
constexpr int NWAVE  = 8;       // k-slices
constexpr int KSLICE = D / NWAVE;   // 256
constexpr int KC     = 32;      // k per MFMA step
constexpr int NKC    = KSLICE / KC; // 8
constexpr int PAD    = 66;
constexpr int NM     = TPB / 16;    // 4 m-tiles per wave

typedef __attribute__((ext_vector_type(8))) short bf16x8;
typedef __attribute__((ext_vector_type(4))) float f32x4;

static __device__ inline unsigned short f2bf_u(float x) {
  __hip_bfloat16 h = __float2bfloat16(x);   // RNE
  unsigned short u; __builtin_memcpy(&u, &h, 2); return u;
}
static __device__ inline float bfu2f(unsigned short u) {
  __hip_bfloat16 h; __builtin_memcpy(&h, &u, 2);
  return __bfloat162float(h);
}

// split 8 f32 into hi/lo bf16 — bit-identical to rounds 2-11
static __device__ inline void cvt_hilo(const float* f, bf16x8& hi, bf16x8& lo) {
#pragma unroll
  for (int j = 0; j < 8; ++j) {
    unsigned short h = f2bf_u(f[j]);
    float hf = bfu2f(h);
    unsigned short lw = f2bf_u(f[j] - hf);
    hi[j] = (short)h;
    lo[j] = (short)lw;
  }
}

// pre-kernel (R11, bit-identical values): W -> FRAGMENT-MAJOR store. Fragment
// (s,kc,ntile,hl) = 1 KB contiguous (64 lanes x 16B) in exact consumption order.
__global__ __launch_bounds__(256)
void prep_w(const float* __restrict__ W, unsigned short* __restrict__ WF) {
  const int i = (blockIdx.x * 256 + threadIdx.x) * 4;
  float4 v = *reinterpret_cast<const float4*>(W + i);
  float f[4] = {v.x, v.y, v.z, v.w};
  const int e  = i / D;            // constant across the 4 elems
  const int lm = e & 15, nt = e >> 4;
#pragma unroll
  for (int j = 0; j < 4; ++j) {
    const int k  = (i + j) % D;
    const int s  = k >> 8;           // k-slice
    const int kc = (k >> 5) & 7;     // 32-k step
    const int lk = (k >> 3) & 3;     // k-group
    const int jj = k & 7;
    const int lane = lk * 16 + lm;
    const size_t base = ((size_t)((s * 8 + kc) * 4 + nt) * 2) * 512 + (size_t)lane * 8 + jj;
    unsigned short h = f2bf_u(f[j]);
    float hf = bfu2f(h);
    WF[base]       = h;                    // hi (hl=0)
    WF[base + 512] = f2bf_u(f[j] - hf);    // lo (hl=1, next 1 KB)
  }
}

__global__ __launch_bounds__(512, 2)
void router_main(const float* __restrict__ X,
                 const unsigned short* __restrict__ WF,
                 const float* __restrict__ bias,
                 float* __restrict__ out) {
  __shared__ float red[4][TPB][PAD];   // 67.6 KB, used twice (k-slices 0-3 then 4-7)
  __shared__ int   i1s[TPB], i2s[TPB];
  __shared__ float p1s[TPB], p2s[TPB];

  const int t  = threadIdx.x;
  const int w  = t >> 6;        // wave id = k-slice
  const int l  = t & 63;
  const int lm = l & 15;        // M-row / N-col in 16x16 tile
  const int lk = l >> 4;        // k-group -> k offset lk*8
  // XCD swizzle: xcd = bid%8 gets contiguous token range
  const int tile = (blockIdx.x & 7) * (NBLK / 8) + (blockIdx.x >> 3);
  const int tok0 = tile * TPB;

  f32x4 acc[NM][4];
#pragma unroll
  for (int m = 0; m < NM; ++m)
#pragma unroll
    for (int n = 0; n < 4; ++n) acc[m][n] = (f32x4){0.f, 0.f, 0.f, 0.f};

  const float* xr[NM];
#pragma unroll
  for (int m = 0; m < NM; ++m)
    xr[m] = X + (size_t)(tok0 + m * 16 + lm) * D + w * KSLICE + lk * 8;

  // X staging, double-buffered one kc ahead (identical to round 8)
  float4 c0[NM], c1[NM];
#pragma unroll
  for (int m = 0; m < NM; ++m) {
    c0[m] = *reinterpret_cast<const float4*>(xr[m]);
    c1[m] = *reinterpret_cast<const float4*>(xr[m] + 4);
  }

#pragma unroll
  for (int kc = 0; kc < NKC; ++kc) {
    // batched B loads: one CONTIGUOUS 8 KB run per (slice,kc) — fragment-major WF
    const unsigned short* gb = WF + ((size_t)((w * 8 + kc) * 4) * 2) * 512 + (size_t)l * 8;
    bf16x8 bh[4], bl[4];
#pragma unroll
    for (int n = 0; n < 4; ++n) {
      bh[n] = *reinterpret_cast<const bf16x8*>(gb + (size_t)(n * 2) * 512);
      bl[n] = *reinterpret_cast<const bf16x8*>(gb + (size_t)(n * 2 + 1) * 512);
    }

    // prefetch next-kc X for all 4 m-tiles (issued after W -> W waits leave X in flight)
    float4 n0[NM], n1[NM];
    if (kc < NKC - 1) {
#pragma unroll
      for (int m = 0; m < NM; ++m) {
        n0[m] = *reinterpret_cast<const float4*>(xr[m] + (kc + 1) * KC);
        n1[m] = *reinterpret_cast<const float4*>(xr[m] + (kc + 1) * KC + 4);
      }
    }

#pragma unroll
    for (int m = 0; m < NM; ++m) {            // frozen kc / hh,hl,lh,ll order
      float f[8];
      *reinterpret_cast<float4*>(&f[0]) = c0[m];
      *reinterpret_cast<float4*>(&f[4]) = c1[m];
      bf16x8 ah, al;
      cvt_hilo(f, ah, al);
#pragma unroll
      for (int n = 0; n < 4; ++n) {
        acc[m][n] = __builtin_amdgcn_mfma_f32_16x16x32_bf16(ah, bh[n], acc[m][n], 0, 0, 0);
        acc[m][n] = __builtin_amdgcn_mfma_f32_16x16x32_bf16(ah, bl[n], acc[m][n], 0, 0, 0);
        acc[m][n] = __builtin_amdgcn_mfma_f32_16x16x32_bf16(al, bh[n], acc[m][n], 0, 0, 0);
        acc[m][n] = __builtin_amdgcn_mfma_f32_16x16x32_bf16(al, bl[n], acc[m][n], 0, 0, 0);
      }
    }
    if (kc < NKC - 1) {
#pragma unroll
      for (int m = 0; m < NM; ++m) { c0[m] = n0[m]; c1[m] = n1[m]; }
    }
  }

  // ---- two-batch cross-wave reduce; bias + w0+...+w7 order exact (rounds 2-11) ----
  const int rtok = t >> 3;          // 0..63
  const int re0  = (t & 7) * 8;     // 0..56
  float s[8];

  if (w < 4) {                       // batch 1: k-slices 0..3 stash
#pragma unroll
    for (int m = 0; m < NM; ++m)
#pragma unroll
      for (int n = 0; n < 4; ++n)
#pragma unroll
        for (int j = 0; j < 4; ++j)
          red[w][m * 16 + lk * 4 + j][n * 16 + lm] = acc[m][n][j];
  }
  __syncthreads();
#pragma unroll
  for (int q = 0; q < 8; ++q) {
    const int e = re0 + q;
    float v = bias[e];
#pragma unroll
    for (int ww = 0; ww < 4; ++ww) v += red[ww][rtok][e];
    s[q] = v;
  }
  __syncthreads();
  if (w >= 4) {                      // batch 2: k-slices 4..7 stash (same buffer)
#pragma unroll
    for (int m = 0; m < NM; ++m)
#pragma unroll
      for (int n = 0; n < 4; ++n)
#pragma unroll
        for (int j = 0; j < 4; ++j)
          red[w - 4][m * 16 + lk * 4 + j][n * 16 + lm] = acc[m][n][j];
  }
  __syncthreads();
#pragma unroll
  for (int q = 0; q < 8; ++q) {
    const int e = re0 + q;
    float v = s[q];
#pragma unroll
    for (int ww = 0; ww < 4; ++ww) v += red[ww][rtok][e];
    red[0][rtok][e] = v;             // 1:1 slot ownership
  }
  __syncthreads();

  // ---- top-2 + softmax weights (threads 0..63, one token each) ----
  if (t < TPB) {
    float m1 = -INFINITY, m2 = -INFINITY;
    int j1 = 0, j2 = 0;
    for (int e = 0; e < NE; ++e) {
      const float v = red[0][t][e];
      if (v > m1) { m2 = m1; j2 = j1; m1 = v; j1 = e; }     // strict >: lax.top_k tie-break
      else if (v > m2) { m2 = v; j2 = e; }
    }
    const float e2  = expf(m2 - m1);
    const float inv = 1.0f / (1.0f + e2);
    i1s[t] = j1; i2s[t] = j2;
    p1s[t] = inv; p2s[t] = e2 * inv;
    float* oidx = out + (size_t)TOKENS * NE + (size_t)(tok0 + t) * 2;
    oidx[0] = (float)j1;
    oidx[1] = (float)j2;
  }
  __syncthreads();

  // ---- coalesced sf write: 512 thr -> (token = t>>3, experts 8*(t&7)..+7) ----
  {
    const int tok = t >> 3;
    const int e0  = (t & 7) * 8;
    const int j1 = i1s[tok], j2 = i2s[tok];
    const float pa = p1s[tok], pb2 = p2s[tok];
    float vv[8];
#pragma unroll
    for (int q = 0; q < 8; ++q) {
      const int e = e0 + q;
      vv[q] = (e == j1) ? pa : ((e == j2) ? pb2 : 0.f);
    }
    float* obase = out + (size_t)(tok0 + tok) * NE + e0;
    *reinterpret_cast<float4*>(obase)     = make_float4(vv[0], vv[1], vv[2], vv[3]);
    *reinterpret_cast<float4*>(obase + 4) = make_float4(vv[4], vv[5], vv[6], vv[7]);
  }
}

extern "C" void kernel_launch(void* const* d_in, const int* in_sizes, int n_in,
                              void* d_out, int out_size, void* d_ws, size_t ws_size,
                              hipStream_t stream) {
  const float* X = (const float*)d_in[0];
  const float* W = (const float*)d_in[1];
  const float* B = (const float*)d_in[2];
  float* out = (float*)d_out;

  unsigned short* WF = (unsigned short*)d_ws;   // 512 KB fragment-major Whi/Wlo

  prep_w<<<dim3(NE * D / (256 * 4)), dim3(256), 0, stream>>>(W, WF);
  router_main<<<dim3(NBLK), dim3(512), 0, stream>>>(X, WF, B, out);
}

// Round 13
// 43.869 us; speedup vs baseline: 2.6348x; 1.0002x over previous
//
#include <hip/hip_runtime.h>
#include <hip/hip_bf16.h>
#include <math.h>

constexpr int D      = 2048;
constexpr int NE     = 64;
constexpr int TOKENS = 16384;   // 4*4096
constexpr int TPB    = 64;      // tokens per block -> 256 blocks, 1/CU, no tail
constexpr int NBLK   = TOKENS / TPB;
constexpr int NWAVE  = 8;       // k-slices
constexpr int KSLICE = D / NWAVE;   // 256
constexpr int KC     = 32;      // k per MFMA step
constexpr int NKC    = KSLICE / KC; // 8
constexpr int PAD    = 66;
constexpr int NM     = TPB / 16;    // 4 m-tiles per wave

typedef __attribute__((ext_vector_type(8))) short bf16x8;
typedef __attribute__((ext_vector_type(4))) float f32x4;

static __device__ inline unsigned short f2bf_u(float x) {
  __hip_bfloat16 h = __float2bfloat16(x);   // RNE
  unsigned short u; __builtin_memcpy(&u, &h, 2); return u;
}
static __device__ inline float bfu2f(unsigned short u) {
  __hip_bfloat16 h; __builtin_memcpy(&h, &u, 2);
  return __bfloat162float(h);
}

// split 8 f32 into hi/lo bf16 — bit-identical to rounds 2-12
static __device__ inline void cvt_hilo(const float* f, bf16x8& hi, bf16x8& lo) {
#pragma unroll
  for (int j = 0; j < 8; ++j) {
    unsigned short h = f2bf_u(f[j]);
    float hf = bfu2f(h);
    unsigned short lw = f2bf_u(f[j] - hf);
    hi[j] = (short)h;
    lo[j] = (short)lw;
  }
}

// pre-kernel (R11/R12, bit-identical values): W -> FRAGMENT-MAJOR store.
// Fragment (s,kc,ntile,hl) = 1 KB contiguous (64 lanes x 16B) in consumption order.
__global__ __launch_bounds__(256)
void prep_w(const float* __restrict__ W, unsigned short* __restrict__ WF) {
  const int i = (blockIdx.x * 256 + threadIdx.x) * 4;
  float4 v = *reinterpret_cast<const float4*>(W + i);
  float f[4] = {v.x, v.y, v.z, v.w};
  const int e  = i / D;
  const int lm = e & 15, nt = e >> 4;
#pragma unroll
  for (int j = 0; j < 4; ++j) {
    const int k  = (i + j) % D;
    const int s  = k >> 8;
    const int kc = (k >> 5) & 7;
    const int lk = (k >> 3) & 3;
    const int jj = k & 7;
    const int lane = lk * 16 + lm;
    const size_t base = ((size_t)((s * 8 + kc) * 4 + nt) * 2) * 512 + (size_t)lane * 8 + jj;
    unsigned short h = f2bf_u(f[j]);
    float hf = bfu2f(h);
    WF[base]       = h;                    // hi (hl=0)
    WF[base + 512] = f2bf_u(f[j] - hf);    // lo (hl=1, next 1 KB)
  }
}

__global__ __launch_bounds__(512)
void router_main(const float* __restrict__ X,
                 const unsigned short* __restrict__ WF,
                 const float* __restrict__ bias,
                 float* __restrict__ out) {
  __shared__ float red[4][TPB][PAD];   // 67.6 KB, used twice
  __shared__ int   i1s[TPB], i2s[TPB];
  __shared__ float p1s[TPB], p2s[TPB];

  const int t  = threadIdx.x;
  const int w  = t >> 6;        // wave id = k-slice
  const int l  = t & 63;
  const int lm = l & 15;
  const int lk = l >> 4;
  const int tile = (blockIdx.x & 7) * (NBLK / 8) + (blockIdx.x >> 3);  // XCD swizzle
  const int tok0 = tile * TPB;

  f32x4 acc[NM][4];
#pragma unroll
  for (int m = 0; m < NM; ++m)
#pragma unroll
    for (int n = 0; n < 4; ++n) acc[m][n] = (f32x4){0.f, 0.f, 0.f, 0.f};

  const float* xr[NM];
#pragma unroll
  for (int m = 0; m < NM; ++m)
    xr[m] = X + (size_t)(tok0 + m * 16 + lm) * D + w * KSLICE + lk * 8;

  // ---- register double-buffers: W (fragment-major, contiguous 8 KB/kc) and X ----
  bf16x8 bhA[4], blA[4], bhB[4], blB[4];
  float4 c0A[NM], c1A[NM], c0B[NM], c1B[NM];

  auto loadW = [&](int kc, bf16x8* bh, bf16x8* bl) {
    const unsigned short* gb = WF + ((size_t)((w * 8 + kc) * 4) * 2) * 512 + (size_t)l * 8;
#pragma unroll
    for (int n = 0; n < 4; ++n) {
      bh[n] = *reinterpret_cast<const bf16x8*>(gb + (size_t)(n * 2) * 512);
      bl[n] = *reinterpret_cast<const bf16x8*>(gb + (size_t)(n * 2 + 1) * 512);
    }
  };
  auto loadX = [&](int kc, float4* c0, float4* c1) {
#pragma unroll
    for (int m = 0; m < NM; ++m) {
      c0[m] = *reinterpret_cast<const float4*>(xr[m] + kc * KC);
      c1[m] = *reinterpret_cast<const float4*>(xr[m] + kc * KC + 4);
    }
  };
  auto compute = [&](const bf16x8* bh, const bf16x8* bl,
                     const float4* c0, const float4* c1) {
#pragma unroll
    for (int m = 0; m < NM; ++m) {            // frozen kc / hh,hl,lh,ll order
      float f[8];
      *reinterpret_cast<float4*>(&f[0]) = c0[m];
      *reinterpret_cast<float4*>(&f[4]) = c1[m];
      bf16x8 ah, al;
      cvt_hilo(f, ah, al);
#pragma unroll
      for (int n = 0; n < 4; ++n) {
        acc[m][n] = __builtin_amdgcn_mfma_f32_16x16x32_bf16(ah, bh[n], acc[m][n], 0, 0, 0);
        acc[m][n] = __builtin_amdgcn_mfma_f32_16x16x32_bf16(ah, bl[n], acc[m][n], 0, 0, 0);
        acc[m][n] = __builtin_amdgcn_mfma_f32_16x16x32_bf16(al, bh[n], acc[m][n], 0, 0, 0);
        acc[m][n] = __builtin_amdgcn_mfma_f32_16x16x32_bf16(al, bl[n], acc[m][n], 0, 0, 0);
      }
    }
  };

  // prologue: kc=0 into buffer A
  loadW(0, bhA, blA);
  loadX(0, c0A, c1A);

#pragma unroll
  for (int kc = 0; kc < NKC; ++kc) {
    if ((kc & 1) == 0) {
      if (kc < NKC - 1) { loadW(kc + 1, bhB, blB); loadX(kc + 1, c0B, c1B); }
      compute(bhA, blA, c0A, c1A);   // waits only on loads issued LAST iteration
    } else {
      if (kc < NKC - 1) { loadW(kc + 1, bhA, blA); loadX(kc + 1, c0A, c1A); }
      compute(bhB, blB, c0B, c1B);
    }
  }

  // ---- two-batch cross-wave reduce; bias + w0+...+w7 order exact (rounds 2-12) ----
  const int rtok = t >> 3;          // 0..63
  const int re0  = (t & 7) * 8;     // 0..56
  float s[8];

  if (w < 4) {                       // batch 1: k-slices 0..3 stash
#pragma unroll
    for (int m = 0; m < NM; ++m)
#pragma unroll
      for (int n = 0; n < 4; ++n)
#pragma unroll
        for (int j = 0; j < 4; ++j)
          red[w][m * 16 + lk * 4 + j][n * 16 + lm] = acc[m][n][j];
  }
  __syncthreads();
#pragma unroll
  for (int q = 0; q < 8; ++q) {
    const int e = re0 + q;
    float v = bias[e];
#pragma unroll
    for (int ww = 0; ww < 4; ++ww) v += red[ww][rtok][e];
    s[q] = v;
  }
  __syncthreads();
  if (w >= 4) {                      // batch 2: k-slices 4..7 stash (same buffer)
#pragma unroll
    for (int m = 0; m < NM; ++m)
#pragma unroll
      for (int n = 0; n < 4; ++n)
#pragma unroll
        for (int j = 0; j < 4; ++j)
          red[w - 4][m * 16 + lk * 4 + j][n * 16 + lm] = acc[m][n][j];
  }
  __syncthreads();
#pragma unroll
  for (int q = 0; q < 8; ++q) {
    const int e = re0 + q;
    float v = s[q];
#pragma unroll
    for (int ww = 0; ww < 4; ++ww) v += red[ww][rtok][e];
    red[0][rtok][e] = v;             // 1:1 slot ownership
  }
  __syncthreads();

  // ---- top-2 + softmax weights (threads 0..63, one token each) ----
  if (t < TPB) {
    float m1 = -INFINITY, m2 = -INFINITY;
    int j1 = 0, j2 = 0;
    for (int e = 0; e < NE; ++e) {
      const float v = red[0][t][e];
      if (v > m1) { m2 = m1; j2 = j1; m1 = v; j1 = e; }     // strict >: lax.top_k tie-break
      else if (v > m2) { m2 = v; j2 = e; }
    }
    const float e2  = expf(m2 - m1);
    const float inv = 1.0f / (1.0f + e2);
    i1s[t] = j1; i2s[t] = j2;
    p1s[t] = inv; p2s[t] = e2 * inv;
    float* oidx = out + (size_t)TOKENS * NE + (size_t)(tok0 + t) * 2;
    oidx[0] = (float)j1;
    oidx[1] = (float)j2;
  }
  __syncthreads();

  // ---- coalesced sf write: 512 thr -> (token = t>>3, experts 8*(t&7)..+7) ----
  {
    const int tok = t >> 3;
    const int e0  = (t & 7) * 8;
    const int j1 = i1s[tok], j2 = i2s[tok];
    const float pa = p1s[tok], pb2 = p2s[tok];
    float vv[8];
#pragma unroll
    for (int q = 0; q < 8; ++q) {
      const int e = e0 + q;
      vv[q] = (e == j1) ? pa : ((e == j2) ? pb2 : 0.f);
    }
    float* obase = out + (size_t)(tok0 + tok) * NE + e0;
    *reinterpret_cast<float4*>(obase)     = make_float4(vv[0], vv[1], vv[2], vv[3]);
    *reinterpret_cast<float4*>(obase + 4) = make_float4(vv[4], vv[5], vv[6], vv[7]);
  }
}

extern "C" void kernel_launch(void* const* d_in, const int* in_sizes, int n_in,
                              void* d_out, int out_size, void* d_ws, size_t ws_size,
                              hipStream_t stream) {
  const float* X = (const float*)d_in[0];
  const float* W = (const float*)d_in[1];
  const float* B = (const float*)d_in[2];
  float* out = (float*)d_out;

  unsigned short* WF = (unsigned short*)d_ws;   // 512 KB fragment-major Whi/Wlo

  prep_w<<<dim3(NE * D / (256 * 4)), dim3(256), 0, stream>>>(W, WF);
  router_main<<<dim3(NBLK), dim3(512), 0, stream>>>(X, WF, B, out);
}

// Round 14
// 42.578 us; speedup vs baseline: 2.7146x; 1.0303x over previous
//
#include <hip/hip_runtime.h>
#include <hip/hip_bf16.h>
#include <math.h>

constexpr int D      = 2048;
constexpr int NE     = 64;
constexpr int TOKENS = 16384;   // 4*4096
constexpr int TPB    = 64;      // tokens per block -> 256 blocks, 1/CU, no tail
constexpr int NBLK   = TOKENS / TPB;
constexpr int NWAVE  = 8;       // k-slices
constexpr int KSLICE = D / NWAVE;   // 256
constexpr int KC     = 32;      // k per MFMA step
constexpr int NKC    = KSLICE / KC; // 8
constexpr int PAD    = 66;
constexpr int NM     = TPB / 16;    // 4 m-tiles per wave

typedef __attribute__((ext_vector_type(8))) short bf16x8;
typedef __attribute__((ext_vector_type(4))) float f32x4;

static __device__ inline unsigned short f2bf_u(float x) {
  __hip_bfloat16 h = __float2bfloat16(x);   // RNE
  unsigned short u; __builtin_memcpy(&u, &h, 2); return u;
}
static __device__ inline float bfu2f(unsigned short u) {
  __hip_bfloat16 h; __builtin_memcpy(&h, &u, 2);
  return __bfloat162float(h);
}

// split 8 f32 into hi/lo bf16 — bit-identical to rounds 2-13
static __device__ inline void cvt_hilo(const float* f, bf16x8& hi, bf16x8& lo) {
#pragma unroll
  for (int j = 0; j < 8; ++j) {
    unsigned short h = f2bf_u(f[j]);
    float hf = bfu2f(h);
    unsigned short lw = f2bf_u(f[j] - hf);
    hi[j] = (short)h;
    lo[j] = (short)lw;
  }
}

// pre-kernel (R11/R12, bit-identical values): W -> FRAGMENT-MAJOR store.
// Fragment (s,kc,ntile,hl) = 1 KB contiguous (64 lanes x 16B) in consumption order.
__global__ __launch_bounds__(256)
void prep_w(const float* __restrict__ W, unsigned short* __restrict__ WF) {
  const int i = (blockIdx.x * 256 + threadIdx.x) * 4;
  float4 v = *reinterpret_cast<const float4*>(W + i);
  float f[4] = {v.x, v.y, v.z, v.w};
  const int e  = i / D;
  const int lm = e & 15, nt = e >> 4;
#pragma unroll
  for (int j = 0; j < 4; ++j) {
    const int k  = (i + j) % D;
    const int s  = k >> 8;
    const int kc = (k >> 5) & 7;
    const int lk = (k >> 3) & 3;
    const int jj = k & 7;
    const int lane = lk * 16 + lm;
    const size_t base = ((size_t)((s * 8 + kc) * 4 + nt) * 2) * 512 + (size_t)lane * 8 + jj;
    unsigned short h = f2bf_u(f[j]);
    float hf = bfu2f(h);
    WF[base]       = h;                    // hi (hl=0)
    WF[base + 512] = f2bf_u(f[j] - hf);    // lo (hl=1, next 1 KB)
  }
}

__global__ __launch_bounds__(512, 1)   // 1 wave/EU floor: full VGPR budget for the pipeline
void router_main(const float* __restrict__ X,
                 const unsigned short* __restrict__ WF,
                 const float* __restrict__ bias,
                 float* __restrict__ out) {
  __shared__ float red[4][TPB][PAD];   // 67.6 KB, used twice
  __shared__ int   i1s[TPB], i2s[TPB];
  __shared__ float p1s[TPB], p2s[TPB];

  const int t  = threadIdx.x;
  const int w  = t >> 6;        // wave id = k-slice
  const int l  = t & 63;
  const int lm = l & 15;
  const int lk = l >> 4;
  const int tile = (blockIdx.x & 7) * (NBLK / 8) + (blockIdx.x >> 3);  // XCD swizzle
  const int tok0 = tile * TPB;

  f32x4 acc[NM][4];
#pragma unroll
  for (int m = 0; m < NM; ++m)
#pragma unroll
    for (int n = 0; n < 4; ++n) acc[m][n] = (f32x4){0.f, 0.f, 0.f, 0.f};

  const float* xr[NM];
#pragma unroll
  for (int m = 0; m < NM; ++m)
    xr[m] = X + (size_t)(tok0 + m * 16 + lm) * D + w * KSLICE + lk * 8;

  // ---- register double-buffers: W (fragment-major, contiguous 8 KB/kc) and X ----
  bf16x8 bhA[4], blA[4], bhB[4], blB[4];
  float4 c0A[NM], c1A[NM], c0B[NM], c1B[NM];

  auto loadW = [&](int kc, bf16x8* bh, bf16x8* bl) {
    const unsigned short* gb = WF + ((size_t)((w * 8 + kc) * 4) * 2) * 512 + (size_t)l * 8;
#pragma unroll
    for (int n = 0; n < 4; ++n) {
      bh[n] = *reinterpret_cast<const bf16x8*>(gb + (size_t)(n * 2) * 512);
      bl[n] = *reinterpret_cast<const bf16x8*>(gb + (size_t)(n * 2 + 1) * 512);
    }
  };
  auto loadX = [&](int kc, float4* c0, float4* c1) {
#pragma unroll
    for (int m = 0; m < NM; ++m) {
      c0[m] = *reinterpret_cast<const float4*>(xr[m] + kc * KC);
      c1[m] = *reinterpret_cast<const float4*>(xr[m] + kc * KC + 4);
    }
  };
  auto compute = [&](const bf16x8* bh, const bf16x8* bl,
                     const float4* c0, const float4* c1) {
#pragma unroll
    for (int m = 0; m < NM; ++m) {            // frozen kc / hh,hl,lh,ll order
      float f[8];
      *reinterpret_cast<float4*>(&f[0]) = c0[m];
      *reinterpret_cast<float4*>(&f[4]) = c1[m];
      bf16x8 ah, al;
      cvt_hilo(f, ah, al);
#pragma unroll
      for (int n = 0; n < 4; ++n) {
        acc[m][n] = __builtin_amdgcn_mfma_f32_16x16x32_bf16(ah, bh[n], acc[m][n], 0, 0, 0);
        acc[m][n] = __builtin_amdgcn_mfma_f32_16x16x32_bf16(ah, bl[n], acc[m][n], 0, 0, 0);
        acc[m][n] = __builtin_amdgcn_mfma_f32_16x16x32_bf16(al, bh[n], acc[m][n], 0, 0, 0);
        acc[m][n] = __builtin_amdgcn_mfma_f32_16x16x32_bf16(al, bl[n], acc[m][n], 0, 0, 0);
      }
    }
  };

  // prologue: kc=0 into buffer A
  loadW(0, bhA, blA);
  loadX(0, c0A, c1A);

#pragma unroll
  for (int kc = 0; kc < NKC; ++kc) {
    if ((kc & 1) == 0) {
      if (kc < NKC - 1) { loadW(kc + 1, bhB, blB); loadX(kc + 1, c0B, c1B); }
      // fence: kc+1 loads may NOT sink below this point; compute may not hoist above.
      __builtin_amdgcn_sched_barrier(0);
      compute(bhA, blA, c0A, c1A);   // waits with vmcnt(16): kc+1 stays in flight
    } else {
      if (kc < NKC - 1) { loadW(kc + 1, bhA, blA); loadX(kc + 1, c0A, c1A); }
      __builtin_amdgcn_sched_barrier(0);
      compute(bhB, blB, c0B, c1B);
    }
  }

  // ---- two-batch cross-wave reduce; bias + w0+...+w7 order exact (rounds 2-13) ----
  const int rtok = t >> 3;          // 0..63
  const int re0  = (t & 7) * 8;     // 0..56
  float s[8];

  if (w < 4) {                       // batch 1: k-slices 0..3 stash
#pragma unroll
    for (int m = 0; m < NM; ++m)
#pragma unroll
      for (int n = 0; n < 4; ++n)
#pragma unroll
        for (int j = 0; j < 4; ++j)
          red[w][m * 16 + lk * 4 + j][n * 16 + lm] = acc[m][n][j];
  }
  __syncthreads();
#pragma unroll
  for (int q = 0; q < 8; ++q) {
    const int e = re0 + q;
    float v = bias[e];
#pragma unroll
    for (int ww = 0; ww < 4; ++ww) v += red[ww][rtok][e];
    s[q] = v;
  }
  __syncthreads();
  if (w >= 4) {                      // batch 2: k-slices 4..7 stash (same buffer)
#pragma unroll
    for (int m = 0; m < NM; ++m)
#pragma unroll
      for (int n = 0; n < 4; ++n)
#pragma unroll
        for (int j = 0; j < 4; ++j)
          red[w - 4][m * 16 + lk * 4 + j][n * 16 + lm] = acc[m][n][j];
  }
  __syncthreads();
#pragma unroll
  for (int q = 0; q < 8; ++q) {
    const int e = re0 + q;
    float v = s[q];
#pragma unroll
    for (int ww = 0; ww < 4; ++ww) v += red[ww][rtok][e];
    red[0][rtok][e] = v;             // 1:1 slot ownership
  }
  __syncthreads();

  // ---- top-2 + softmax weights (threads 0..63, one token each) ----
  if (t < TPB) {
    float m1 = -INFINITY, m2 = -INFINITY;
    int j1 = 0, j2 = 0;
    for (int e = 0; e < NE; ++e) {
      const float v = red[0][t][e];
      if (v > m1) { m2 = m1; j2 = j1; m1 = v; j1 = e; }     // strict >: lax.top_k tie-break
      else if (v > m2) { m2 = v; j2 = e; }
    }
    const float e2  = expf(m2 - m1);
    const float inv = 1.0f / (1.0f + e2);
    i1s[t] = j1; i2s[t] = j2;
    p1s[t] = inv; p2s[t] = e2 * inv;
    float* oidx = out + (size_t)TOKENS * NE + (size_t)(tok0 + t) * 2;
    oidx[0] = (float)j1;
    oidx[1] = (float)j2;
  }
  __syncthreads();

  // ---- coalesced sf write: 512 thr -> (token = t>>3, experts 8*(t&7)..+7) ----
  {
    const int tok = t >> 3;
    const int e0  = (t & 7) * 8;
    const int j1 = i1s[tok], j2 = i2s[tok];
    const float pa = p1s[tok], pb2 = p2s[tok];
    float vv[8];
#pragma unroll
    for (int q = 0; q < 8; ++q) {
      const int e = e0 + q;
      vv[q] = (e == j1) ? pa : ((e == j2) ? pb2 : 0.f);
    }
    float* obase = out + (size_t)(tok0 + tok) * NE + e0;
    *reinterpret_cast<float4*>(obase)     = make_float4(vv[0], vv[1], vv[2], vv[3]);
    *reinterpret_cast<float4*>(obase + 4) = make_float4(vv[4], vv[5], vv[6], vv[7]);
  }
}

extern "C" void kernel_launch(void* const* d_in, const int* in_sizes, int n_in,
                              void* d_out, int out_size, void* d_ws, size_t ws_size,
                              hipStream_t stream) {
  const float* X = (const float*)d_in[0];
  const float* W = (const float*)d_in[1];
  const float* B = (const float*)d_in[2];
  float* out = (float*)d_out;

  unsigned short* WF = (unsigned short*)d_ws;   // 512 KB fragment-major Whi/Wlo

  prep_w<<<dim3(NE * D / (256 * 4)), dim3(256), 0, stream>>>(W, WF);
  router_main<<<dim3(NBLK), dim3(512), 0, stream>>>(X, WF, B, out);
}